// Round 3
// baseline (571.948 us; speedup 1.0000x reference)
//
#include <hip/hip_runtime.h>
#include <hip/hip_bf16.h>

// ConvEmbedding: out[b,t,c] = bias[c] + sum_k W[c, x[b,t+k-4], k]
// B=8, T=4096, H=512, V=32000, K=9.
//
// R3: fused scatter (overlap-add). No Wt intermediate, no bf16.
//  hist -> scan -> CSR occurrence lists -> out=bias -> per-W-tile scatter:
//  load W tile coalesced along m=(v,k), LDS-transpose, atomicAdd c-contiguous
//  64-lane rows into out[b, s+4-k, c0..c0+63].
// Traffic: 590 MB W read + 67 MB init + ~600 MB f32 atomic RMW.

#define Hc 512
#define Vc 32000
#define Kc 9
#define Tc 4096
#define Bc 8
#define Mc (Vc * Kc)      // 288000
#define VT 7              // vocab rows per tile (7*9=63 m)
#define NVT 4572          // ceil(32000/7)

// ---- K1: histogram of token ids ----
__global__ __launch_bounds__(256) void hist_kernel(
    const int* __restrict__ x, int* __restrict__ hist) {
  const int i = blockIdx.x * 256 + threadIdx.x;  // B*T = 32768
  atomicAdd(&hist[x[i]], 1);
}

// ---- K2: exclusive scan hist[0..V) -> offs[0..V] (single block) ----
__global__ __launch_bounds__(256) void scan_kernel(
    const int* __restrict__ hist, int* __restrict__ offs) {
  __shared__ int wsum[4];
  __shared__ int carry;
  const int tid = threadIdx.x;
  const int lane = tid & 63;
  const int w = tid >> 6;
  if (tid == 0) carry = 0;
  __syncthreads();
  for (int base = 0; base < Vc; base += 256) {
    const int v = hist[base + tid];
    int incl = v;
#pragma unroll
    for (int d = 1; d < 64; d <<= 1) {
      const int n = __shfl_up(incl, d, 64);
      if (lane >= d) incl += n;
    }
    if (lane == 63) wsum[w] = incl;
    __syncthreads();
    int wpref = 0;
#pragma unroll
    for (int q = 0; q < 3; ++q) wpref += (q < w) ? wsum[q] : 0;
    const int c = carry;
    offs[base + tid] = c + wpref + incl - v;
    __syncthreads();
    if (tid == 255) carry = c + wpref + incl;
    __syncthreads();
  }
  if (tid == 0) offs[Vc] = carry;
}

// ---- K3: fill occurrence lists: list[offs[v]+j] = (b<<12)|s ----
__global__ __launch_bounds__(256) void fill_kernel(
    const int* __restrict__ x, const int* __restrict__ offs,
    int* __restrict__ cursor, int* __restrict__ list) {
  const int i = blockIdx.x * 256 + threadIdx.x;
  const int v = x[i];
  const int pos = atomicAdd(&cursor[v], 1);
  list[offs[v] + pos] = i;  // i = (b<<12)|s since T=4096
}

// ---- K4: out[b,t,c] = bias[c] ----
__global__ __launch_bounds__(256) void init_out_kernel(
    const float* __restrict__ bias, float4* __restrict__ out4) {
  const int tid = threadIdx.x;
  const float4 b4 = ((const float4*)bias)[tid & 127];
  const size_t base = (size_t)blockIdx.x * 8192;  // 8192 float4 per block
  const int r = tid >> 7;                         // 0..1
#pragma unroll
  for (int j = 0; j < 32; ++j)
    out4[base + (size_t)(r + 2 * j) * 128 + (tid & 127)] = b4;
}

// ---- K5: scatter-add ----
// grid = (NVT, H/64). Load W[c0..c0+63][m0..m0+nm) via LDS transpose, then
// for each occurrence of each v in tile: atomicAdd 64-c row into out.
__global__ __launch_bounds__(256) void scatter_kernel(
    const float* __restrict__ W, const int* __restrict__ offs,
    const int* __restrict__ list, float* __restrict__ out) {
  __shared__ float tile[63][65];  // [m_local][c_local], pad -> conflict-free
  const int v0 = blockIdx.x * VT;
  const int nv = (Vc - v0 < VT) ? (Vc - v0) : VT;
  const int beg = offs[v0];
  const int end = offs[v0 + nv];
  if (beg == end) return;  // no token uses this vocab range
  const int c0 = blockIdx.y * 64;
  const int tid = threadIdx.x;
  const int tx = tid & 63;   // m_local on load, c_local on scatter
  const int g = tid >> 6;    // 0..3
  const int m0 = v0 * Kc;
  const int nm = nv * Kc;    // up to 63
  if (tx < nm) {
    const size_t rowbase = (size_t)(c0 + g) * Mc + m0 + tx;
#pragma unroll
    for (int r = 0; r < 16; ++r) {
      // c row = g + 4*r covers 0..63 across the 4 thread groups
      tile[tx][g + 4 * r] = W[rowbase + (size_t)(4 * r) * Mc];
    }
  }
  __syncthreads();
  for (int vl = 0; vl < nv; ++vl) {
    const int b0 = offs[v0 + vl];
    const int e0 = offs[v0 + vl + 1];
    for (int j = b0; j < e0; ++j) {
      const int e = list[j];      // (b<<12)|s
      const int s = e & 4095;
      const int brow = (e >> 12) * Tc;
#pragma unroll
      for (int k = g; k < Kc; k += 4) {
        const int t = s + 4 - k;
        if ((unsigned)t < (unsigned)Tc) {
          atomicAdd(&out[((size_t)(brow + t) << 9) + c0 + tx],
                    tile[vl * Kc + k][tx]);
        }
      }
    }
  }
}

// ---- Fallback (ws too small): direct, slow but correct ----
__global__ __launch_bounds__(256) void conv_fallback_kernel(
    const int* __restrict__ x, const float* __restrict__ W,
    const float* __restrict__ bias, float* __restrict__ out) {
  const size_t idx = (size_t)blockIdx.x * 256 + threadIdx.x;
  const int c = (int)(idx & (Hc - 1));
  const size_t bt = idx >> 9;
  const int t = (int)(bt & (Tc - 1));
  const int b = (int)(bt >> 12);
  float acc = bias[c];
#pragma unroll
  for (int k = 0; k < Kc; ++k) {
    const int s = t + k - (Kc / 2);
    if (s >= 0 && s < Tc) {
      const int id = x[b * Tc + s];
      acc += W[(size_t)c * Mc + (size_t)id * Kc + k];
    }
  }
  out[idx] = acc;
}

extern "C" void kernel_launch(void* const* d_in, const int* in_sizes, int n_in,
                              void* d_out, int out_size, void* d_ws, size_t ws_size,
                              hipStream_t stream) {
  const int* x = (const int*)d_in[0];
  const float* W = (const float*)d_in[1];
  const float* bias = (const float*)d_in[2];
  float* out = (float*)d_out;

  // ws layout: hist[V], offs[V+1], cursor[V], list[B*T]
  const size_t hist_off = 0;
  const size_t offs_off = hist_off + (size_t)Vc * 4;
  const size_t curs_off = offs_off + (size_t)(Vc + 1) * 4;
  const size_t list_off = curs_off + (size_t)Vc * 4;
  const size_t need = list_off + (size_t)Bc * Tc * 4;

  if (ws_size >= need) {
    int* hist = (int*)((char*)d_ws + hist_off);
    int* offs = (int*)((char*)d_ws + offs_off);
    int* cursor = (int*)((char*)d_ws + curs_off);
    int* list = (int*)((char*)d_ws + list_off);
    hipMemsetAsync(hist, 0, (size_t)Vc * 4, stream);
    hipMemsetAsync(cursor, 0, (size_t)Vc * 4, stream);
    hist_kernel<<<(Bc * Tc) / 256, 256, 0, stream>>>(x, hist);
    scan_kernel<<<1, 256, 0, stream>>>(hist, offs);
    fill_kernel<<<(Bc * Tc) / 256, 256, 0, stream>>>(x, offs, cursor, list);
    init_out_kernel<<<512, 256, 0, stream>>>(bias, (float4*)out);
    dim3 g5(NVT, Hc / 64);
    scatter_kernel<<<g5, 256, 0, stream>>>(W, offs, list, out);
  } else {
    const size_t n = (size_t)Bc * Tc * Hc;
    conv_fallback_kernel<<<(int)(n / 256), 256, 0, stream>>>(x, W, bias, out);
  }
}

// Round 4
// 244.408 us; speedup vs baseline: 2.3401x; 2.3401x over previous
//
#include <hip/hip_runtime.h>
#include <hip/hip_bf16.h>

// ConvEmbedding: out[b,t,c] = bias[c] + sum_k W[c, x[b,t+k-4], k]
// B=8, T=4096, H=512, V=32000, K=9.
//
// R4: chunked-c (4 x 128 channels) two-phase with L3-resident compact Wt and
// software-pipelined fused launches: launch i = transpose(chunk i+1 -> bufA)
// || gather(chunk i <- bufB), roles interleaved 1-in-10 by blockIdx.x so the
// L3-bound gather hides under the HBM-bound transpose. No atomics on out.

#define Hc 512
#define Vc 32000
#define Kc 9
#define Tc 4096
#define Bc 8
#define Mc (Vc * Kc)        // 288000
#define CHUNK_C 128
#define NCHUNK 4
#define ROW_U (Kc * CHUNK_C / 2)  // 576 uints = 2304 B per Wt row per chunk
#define WT_ROWS (Vc + 1)          // worst case all distinct + zero row
#define T_TILE 32
#define NTB 9000                  // transpose blocks per chunk: 4500 m-tiles x 2 c-tiles
#define NGB 1024                  // gather blocks per chunk: 8 b x 128 t-tiles

__device__ __forceinline__ unsigned short f2bf(float f) {
  unsigned int u = __float_as_uint(f);
  u += 0x7FFFu + ((u >> 16) & 1u);  // round-to-nearest-even
  return (unsigned short)(u >> 16);
}

// Assign compact slots (1..) to touched vocab ids; slot[] pre-set -1. Slot 0
// is the zero row (sequence-boundary padding).
__global__ __launch_bounds__(256) void mark_kernel(
    const int* __restrict__ x, int* __restrict__ slot, int* __restrict__ counter) {
  const int i = blockIdx.x * 256 + threadIdx.x;  // B*T = 32768
  const int v = x[i];
  if (atomicCAS(&slot[v], -1, -2147483647) == -1) {
    slot[v] = 1 + atomicAdd(counter, 1);
  }
}

// One kernel, two block roles selected by blockIdx.x % 10:
//  rem != 9 -> transpose block for chunk `tchunk` (skipped when tchunk >= NCHUNK)
//  rem == 9 -> gather block for chunk `gchunk`   (skipped when gchunk < 0)
__global__ __launch_bounds__(256) void fused_kernel(
    const float* __restrict__ W, const int* __restrict__ x,
    const int* __restrict__ slot, const float* __restrict__ bias,
    float* __restrict__ out, unsigned int* __restrict__ wbuf,
    const unsigned int* __restrict__ rbuf, int tchunk, int gchunk) {
  __shared__ float tile[64][65];  // transpose scratch; gather aliases ids[]
  const int bx = blockIdx.x;
  const int rem = bx % 10;
  const int tid = threadIdx.x;

  if (rem != 9) {
    // ---------------- transpose role ----------------
    if (tchunk >= NCHUNK) return;
    const int tb = (bx / 10) * 9 + rem;  // 0..9215
    if (tb >= NTB) return;
    const int mt = tb % 4500;
    const int ct = tb / 4500;            // 0..1 (which 64-c half of the chunk)
    const int m0 = mt * 64;
    const int cbase = tchunk * CHUNK_C + ct * 64;
    const int tx = tid & 63;
    const int ty = tid >> 6;  // 0..3
#pragma unroll
    for (int r = 0; r < 16; ++r) {
      const int row = ty * 16 + r;  // c_local 0..63
      tile[row][tx] = W[(size_t)(cbase + row) * Mc + (m0 + tx)];
    }
    __syncthreads();
    const int u = tid & 31;   // uint (c-pair) index within 64-c half
    const int rl = tid >> 5;  // 0..7
#pragma unroll
    for (int p = 0; p < 8; ++p) {
      const int mrow = p * 8 + rl;  // 0..63
      const int m = m0 + mrow;
      const int v = m / Kc;
      const int k = m - v * Kc;
      const int s = slot[v];
      if (s >= 0) {
        const unsigned int val =
            (unsigned int)f2bf(tile[2 * u][mrow]) |
            ((unsigned int)f2bf(tile[2 * u + 1][mrow]) << 16);
        wbuf[(size_t)s * ROW_U + k * (CHUNK_C / 2) + ct * 32 + u] = val;
      }
    }
  } else {
    // ---------------- gather role ----------------
    if (gchunk < 0) return;
    const int gb = bx / 10;  // 0..1023
    int* ids = (int*)tile;   // 40 entries
    const int b = gb >> 7;
    const int t0 = (gb & 127) * T_TILE;
    if (tid < T_TILE + Kc - 1) {
      const int s = t0 + tid - (Kc / 2);
      ids[tid] = (s >= 0 && s < Tc) ? slot[x[b * Tc + s]] : 0;
    }
    __syncthreads();
    const int lane = tid & 63;
    const int w = tid >> 6;  // 0..3: wave handles tt = w*8 .. w*8+7
    const int c0 = gchunk * CHUNK_C;
    const int cpair = c0 + 2 * lane;
    const float2 b2 = *(const float2*)(bias + cpair);
#pragma unroll
    for (int i = 0; i < 8; ++i) {
      const int tt = w * 8 + i;
      float2 acc = b2;
#pragma unroll
      for (int k = 0; k < Kc; ++k) {
        const int id = ids[tt + k];
        const unsigned int wv = rbuf[(size_t)id * ROW_U + k * (CHUNK_C / 2) + lane];
        acc.x += __uint_as_float(wv << 16);
        acc.y += __uint_as_float(wv & 0xFFFF0000u);
      }
      *(float2*)(out + ((size_t)(b * Tc + t0 + tt) << 9) + cpair) = acc;
    }
  }
}

// Fallback (ws too small): direct, slow but correct.
__global__ __launch_bounds__(256) void conv_fallback_kernel(
    const int* __restrict__ x, const float* __restrict__ W,
    const float* __restrict__ bias, float* __restrict__ out) {
  const size_t idx = (size_t)blockIdx.x * 256 + threadIdx.x;
  const int c = (int)(idx & (Hc - 1));
  const size_t bt = idx >> 9;
  const int t = (int)(bt & (Tc - 1));
  const int b = (int)(bt >> 12);
  float acc = bias[c];
#pragma unroll
  for (int k = 0; k < Kc; ++k) {
    const int s = t + k - (Kc / 2);
    if (s >= 0 && s < Tc) {
      const int id = x[b * Tc + s];
      acc += W[(size_t)c * Mc + (size_t)id * Kc + k];
    }
  }
  out[idx] = acc;
}

extern "C" void kernel_launch(void* const* d_in, const int* in_sizes, int n_in,
                              void* d_out, int out_size, void* d_ws, size_t ws_size,
                              hipStream_t stream) {
  const int* x = (const int*)d_in[0];
  const float* W = (const float*)d_in[1];
  const float* bias = (const float*)d_in[2];
  float* out = (float*)d_out;

  // ws layout: buf0, buf1 (worst-case WT_ROWS rows each), slot[V], counter
  const size_t buf_bytes = (size_t)WT_ROWS * ROW_U * 4;  // 73,730,304 B
  const size_t buf1_off = buf_bytes;
  const size_t slot_off = 2 * buf_bytes;
  const size_t cnt_off = slot_off + (size_t)Vc * 4;
  const size_t need = cnt_off + 4;

  if (ws_size >= need) {
    unsigned int* buf0 = (unsigned int*)d_ws;
    unsigned int* buf1 = (unsigned int*)((char*)d_ws + buf1_off);
    int* slot = (int*)((char*)d_ws + slot_off);
    int* counter = (int*)((char*)d_ws + cnt_off);
    hipMemsetAsync(slot, 0xFF, (size_t)Vc * 4, stream);
    hipMemsetAsync(counter, 0, 4, stream);
    hipMemsetAsync(buf0, 0, ROW_U * 4, stream);  // zero row (slot 0)
    hipMemsetAsync(buf1, 0, ROW_U * 4, stream);
    mark_kernel<<<(Bc * Tc) / 256, 256, 0, stream>>>(x, slot, counter);
    const int grid = 10240;
    for (int l = 0; l <= NCHUNK; ++l) {
      const int tchunk = l;          // 4 means "no transpose this launch"
      const int gchunk = l - 1;      // -1 means "no gather this launch"
      unsigned int* wbuf = (tchunk & 1) ? buf1 : buf0;
      const unsigned int* rbuf = (gchunk >= 0 && (gchunk & 1)) ? buf1 : buf0;
      fused_kernel<<<grid, 256, 0, stream>>>(W, x, slot, bias, out, wbuf, rbuf,
                                             tchunk, gchunk);
    }
  } else {
    const size_t n = (size_t)Bc * Tc * Hc;
    conv_fallback_kernel<<<(int)(n / 256), 256, 0, stream>>>(x, W, bias, out);
  }
}